// Round 14
// baseline (56.047 us; speedup 1.0000x reference)
//
#include <hip/hip_runtime.h>

// SelfAttentionHead: B=16, T=1024, C=768, H=64, fp32 in/out, causal softmax.
// wtrans: W -> Wt[192][768] f16.
// proj:   R9 register-staged LDS GEMM, prefetch depth 2 (unchanged, ~HBM floor).
// attn:   32x32-MFMA flash, 128-row Q-tile x 4 waves, KVBLK=64 in LDS.
//         Swapped QK^T (lane&31=q) => in-lane softmax; cross-half reduce via
//         __shfl_xor(.,32); P->PV A-frags via per-wave LDS round-trip
//         (ds_write_b64 x8 / ds_read_b64 x8, 2-way banks). No permlane.
// comb:   identity-layout LSE merge.

typedef _Float16 half8 __attribute__((ext_vector_type(8)));
typedef _Float16 half4 __attribute__((ext_vector_type(4)));
typedef float float4v __attribute__((ext_vector_type(4)));
typedef float f32x16 __attribute__((ext_vector_type(16)));
typedef unsigned int uint2v __attribute__((ext_vector_type(2)));

#define NB   16
#define NT   1024
#define NC   768
#define NH   64

typedef __attribute__((address_space(3))) unsigned int lds_u32_t;
typedef const __attribute__((address_space(1))) unsigned int g_u32_t;

__device__ __forceinline__ void gload16(const void* g, void* l) {
    __builtin_amdgcn_global_load_lds((g_u32_t*)g, (lds_u32_t*)l, 16, 0, 0);
}

__device__ __forceinline__ int swz8(int r) { return (r + (r >> 3)) & 7; }

// ---------------------------------------------------------------------------
// Wt[m*64+col][k] = Wm[k][col]. Grid (48,3) x 256.  (unchanged)
// ---------------------------------------------------------------------------
__global__ __launch_bounds__(256) void wtrans_kernel(
    const float* __restrict__ Wq, const float* __restrict__ Wk,
    const float* __restrict__ Wv, _Float16* __restrict__ Wt)
{
    __shared__ float tile[16][68];
    const int m = blockIdx.y;
    const float* W = (m == 0) ? Wq : (m == 1) ? Wk : Wv;
    const int s = blockIdx.x;
    const int t = threadIdx.x;
    {
        const int kr = t >> 4, c4 = (t & 15) * 4;
        float4v v = *(const float4v*)(W + (size_t)(s * 16 + kr) * NH + c4);
        tile[kr][c4 + 0] = v[0]; tile[kr][c4 + 1] = v[1];
        tile[kr][c4 + 2] = v[2]; tile[kr][c4 + 3] = v[3];
    }
    __syncthreads();
    const int col = t >> 2, j = t & 3;
    half4 h;
#pragma unroll
    for (int i = 0; i < 4; ++i) h[i] = (_Float16)tile[j * 4 + i][col];
    *(half4*)(Wt + (size_t)(m * 64 + col) * NC + s * 16 + j * 4) = h;
}

// ---------------------------------------------------------------------------
// proj: grid 512 x 256 thr. BM=32, BK=64, depth-2 register prefetch. (unchanged)
// ---------------------------------------------------------------------------
__global__ __launch_bounds__(256) void proj_kernel(
    const float* __restrict__ x, const _Float16* __restrict__ Wt,
    _Float16* __restrict__ Qb, _Float16* __restrict__ Kb,
    _Float16* __restrict__ Vt)
{
    __shared__ _Float16 xl[32][68];

    const int t   = threadIdx.x;
    const int wid = t >> 6, lane = t & 63;
    const int l15 = lane & 15, lhi = lane >> 4;
    const int m0  = blockIdx.x * 32;
    const int srow = t >> 3, sc0 = (t & 7) * 8;

    const float*    xsrc  = x  + (size_t)(m0 + srow) * NC + sc0;
    const _Float16* wbase = Wt + (size_t)(wid * 48 + l15) * NC + lhi * 8;

    float4v acc[2][3];
#pragma unroll
    for (int i = 0; i < 2; ++i)
#pragma unroll
        for (int j = 0; j < 3; ++j)
            acc[i][j] = (float4v){0.f, 0.f, 0.f, 0.f};

    float4v g0[2], g1[2];
    half8 bf[2][3][2];
#pragma unroll
    for (int p = 0; p < 2; ++p) {
        g0[p] = *(const float4v*)(xsrc + p * 64);
        g1[p] = *(const float4v*)(xsrc + p * 64 + 4);
#pragma unroll
        for (int nf = 0; nf < 3; ++nf)
#pragma unroll
            for (int ks = 0; ks < 2; ++ks)
                bf[p][nf][ks] = *(const half8*)(wbase + (size_t)nf * 16 * NC
                                                + p * 64 + ks * 32);
    }

#pragma unroll 2
    for (int kc = 0; kc < 12; ++kc) {
        const int cur = kc & 1;
        __syncthreads();
        {
            half8 h;
            h[0] = (_Float16)g0[cur][0]; h[1] = (_Float16)g0[cur][1];
            h[2] = (_Float16)g0[cur][2]; h[3] = (_Float16)g0[cur][3];
            h[4] = (_Float16)g1[cur][0]; h[5] = (_Float16)g1[cur][1];
            h[6] = (_Float16)g1[cur][2]; h[7] = (_Float16)g1[cur][3];
            *(half8*)&xl[srow][sc0] = h;
        }
        __syncthreads();

        half8 bcur[3][2];
#pragma unroll
        for (int nf = 0; nf < 3; ++nf)
#pragma unroll
            for (int ks = 0; ks < 2; ++ks) bcur[nf][ks] = bf[cur][nf][ks];

        if (kc + 2 < 12) {
            g0[cur] = *(const float4v*)(xsrc + (kc + 2) * 64);
            g1[cur] = *(const float4v*)(xsrc + (kc + 2) * 64 + 4);
#pragma unroll
            for (int nf = 0; nf < 3; ++nf)
#pragma unroll
                for (int ks = 0; ks < 2; ++ks)
                    bf[cur][nf][ks] = *(const half8*)(wbase + (size_t)nf * 16 * NC
                                                      + (kc + 2) * 64 + ks * 32);
        }

        half8 af[2][2];
#pragma unroll
        for (int mf = 0; mf < 2; ++mf)
#pragma unroll
            for (int ks = 0; ks < 2; ++ks)
                af[mf][ks] = *(const half8*)&xl[mf * 16 + l15][ks * 32 + lhi * 8];

#pragma unroll
        for (int ks = 0; ks < 2; ++ks)
#pragma unroll
            for (int mf = 0; mf < 2; ++mf)
#pragma unroll
                for (int nf = 0; nf < 3; ++nf)
                    acc[mf][nf] = __builtin_amdgcn_mfma_f32_16x16x32_f16(
                        af[mf][ks], bcur[nf][ks], acc[mf][nf], 0, 0, 0);
    }

#pragma unroll
    for (int nf = 0; nf < 3; ++nf) {
        const int gc  = wid * 48 + nf * 16;
        const int sel = gc >> 6;
        const int col = (gc & 63) + l15;
#pragma unroll
        for (int mf = 0; mf < 2; ++mf) {
            const int row0 = m0 + mf * 16 + lhi * 4;
            if (sel == 2) {
                const int bb = row0 >> 10, tt = row0 & 1023;
                half4 h;
#pragma unroll
                for (int r = 0; r < 4; ++r) h[r] = (_Float16)acc[mf][nf][r];
                *(half4*)(Vt + ((size_t)(bb * 64 + col)) * NT + tt) = h;
            } else {
                _Float16* D = (sel == 0) ? Qb : Kb;
#pragma unroll
                for (int r = 0; r < 4; ++r)
                    D[(size_t)(row0 + r) * NH + col] = (_Float16)acc[mf][nf][r];
            }
        }
    }
}

// ---------------------------------------------------------------------------
// attn partial: grid (36,16) x 256 (4 waves). Job i = 35-bx -> (qi, c):
// Q-tile qi (128 rows; wave w owns rows qi*128+w*32..+32), KV tiles [2c, 2c+2).
// 32x32x16 MFMA; swapped QK^T: lane&31 = q.
// C/D layout (verified): col=lane&31, row=(reg&3)+8*(reg>>2)+4*(lane>>5).
// ---------------------------------------------------------------------------
__global__ __launch_bounds__(256) void attn_part_kernel(
    const _Float16* __restrict__ Qb, const _Float16* __restrict__ Kb,
    const _Float16* __restrict__ Vt, unsigned int* __restrict__ partO,
    float* __restrict__ partML)
{
    __shared__ _Float16 Kl[2][64 * 64];   // 8 KB per buf
    __shared__ _Float16 Vl[2][64 * 64];
    __shared__ _Float16 Pl[4][32][68];    // per-wave P buffer (+4 pad)
    __shared__ float escl[4][32];

    const int tid = threadIdx.x, lane = tid & 63, w = tid >> 6;
    const int l31 = lane & 31, h = lane >> 5;
    const int b = blockIdx.y;
    const int i = 35 - blockIdx.x;       // heavy jobs first

    int qi = 0, st = 0;
    {
        const int starts[8] = {0, 1, 3, 6, 10, 15, 21, 28};
#pragma unroll
        for (int k = 1; k < 8; ++k)
            if (i >= starts[k]) { qi = k; st = starts[k]; }
    }
    const int c     = i - st;
    const int t0    = 2 * c;
    const int wlast = 2 * qi + (w >> 1);          // last causal tile for this wave
    const int qg    = qi * 128 + w * 32 + l31;    // this lane's q (global in batch)

    // Q B-frags: col=lane&31=q, per-mfma k = h*8+e, channel chunk cc*16
    half8 qf[4];
    {
        const _Float16* qp = Qb + ((size_t)(b * NT + qg)) * NH + 8 * h;
#pragma unroll
        for (int cc = 0; cc < 4; ++cc) qf[cc] = *(const half8*)(qp + 16 * cc);
    }

    // staging: slot s: row=s>>3, c8=s&7; LDS[row][c8] = G[row][c8 ^ swz8(row)]
    const int s1 = w * 64 + lane, s2 = 256 + w * 64 + lane;
    const int r1 = s1 >> 3, c1 = (s1 & 7) ^ swz8(r1);
    const int r2 = s2 >> 3, c2 = (s2 & 7) ^ swz8(r2);
    const _Float16* ksrc1 = Kb + ((size_t)(b * NT + r1)) * NH + c1 * 8;
    const _Float16* ksrc2 = Kb + ((size_t)(b * NT + r2)) * NH + c2 * 8;
    const _Float16* vsrc1 = Vt + ((size_t)(b * 64 + r1)) * NT + c1 * 8;
    const _Float16* vsrc2 = Vt + ((size_t)(b * 64 + r2)) * NT + c2 * 8;

    auto STAGE = [&](int jt, int buf) {
        gload16(ksrc1 + (size_t)jt * 64 * NH, &Kl[buf][(size_t)(w * 64) * 8]);
        gload16(ksrc2 + (size_t)jt * 64 * NH, &Kl[buf][(size_t)(256 + w * 64) * 8]);
        gload16(vsrc1 + jt * 64, &Vl[buf][(size_t)(w * 64) * 8]);
        gload16(vsrc2 + jt * 64, &Vl[buf][(size_t)(256 + w * 64) * 8]);
    };

    f32x16 o[2];
#pragma unroll
    for (int d = 0; d < 2; ++d)
#pragma unroll
        for (int r = 0; r < 16; ++r) o[d][r] = 0.f;
    float m2 = -1e30f, lsum = 0.f;

    STAGE(t0, 0);
    asm volatile("s_waitcnt vmcnt(0)" ::: "memory");
    __syncthreads();

#pragma unroll
    for (int tix = 0; tix < 2; ++tix) {
        const int jt = t0 + tix;
        if (tix == 0) STAGE(t0 + 1, 1);

        if (jt <= wlast) {
            // S^T = K * Q^T : A=K (row=k token), B=Q (col=q)
            f32x16 sT[2];
            __builtin_amdgcn_s_setprio(1);
#pragma unroll
            for (int kb = 0; kb < 2; ++kb) {
                const int row = kb * 32 + l31;
                const int sw = swz8(row);
                f32x16 sv;
#pragma unroll
                for (int r = 0; r < 16; ++r) sv[r] = 0.f;
#pragma unroll
                for (int cc = 0; cc < 4; ++cc) {
                    half8 ka = *(const half8*)&Kl[tix][row * 64
                                  + (((2 * cc + h) ^ sw) * 8)];
                    sv = __builtin_amdgcn_mfma_f32_32x32x16_f16(ka, qf[cc], sv, 0, 0, 0);
                }
                sT[kb] = sv;
            }
            __builtin_amdgcn_s_setprio(0);

            // scale (log2 domain) + causal mask + in-lane max over 32 k-rows
            const float SC = 0.18033688f;   // 0.125 * log2(e)
            const bool dm = (jt == wlast);
            float p[2][16];
            float mt = -1e30f;
#pragma unroll
            for (int kb = 0; kb < 2; ++kb)
#pragma unroll
                for (int r = 0; r < 16; ++r) {
                    float v = sT[kb][r] * SC;
                    if (dm) {
                        const int kpos = jt * 64 + kb * 32 + (r & 3) + 8 * (r >> 2) + 4 * h;
                        if (kpos > qg) v = -1e30f;
                    }
                    p[kb][r] = v;
                    mt = fmaxf(mt, v);
                }
            mt = fmaxf(mt, __shfl_xor(mt, 32));   // cross-half (other 32 k-rows)

            if (tix == 0) {
                m2 = mt;                   // first tile of job: o==0, no rescale
            } else if (__any(mt - m2 > 4.0f)) {
                const float mnew = fmaxf(m2, mt);
                const float esc  = exp2f(m2 - mnew);
                if (lane < 32) escl[w][l31] = esc;
                asm volatile("s_waitcnt lgkmcnt(0)" ::: "memory");
                __builtin_amdgcn_sched_barrier(0);
#pragma unroll
                for (int d = 0; d < 2; ++d)
#pragma unroll
                    for (int r = 0; r < 16; ++r)
                        o[d][r] *= escl[w][(r & 3) + 8 * (r >> 2) + 4 * h];
                lsum *= esc;
                m2 = mnew;
            }

            float ps = 0.f;
#pragma unroll
            for (int kb = 0; kb < 2; ++kb)
#pragma unroll
                for (int r = 0; r < 16; ++r) {
                    const float e = exp2f(p[kb][r] - m2);
                    p[kb][r] = e;
                    ps += e;
                }
            ps += __shfl_xor(ps, 32);
            lsum += ps;

            // pack P pairs; pk[kb*8+rp] = k-rows (kb*32+4h+) {0,1},{2,3},{8,9},...
            unsigned int pk[16];
#pragma unroll
            for (int kb = 0; kb < 2; ++kb)
#pragma unroll
                for (int rp = 0; rp < 8; ++rp) {
                    auto h2 = __builtin_amdgcn_cvt_pkrtz(p[kb][2 * rp], p[kb][2 * rp + 1]);
                    pk[kb * 8 + rp] = __builtin_bit_cast(unsigned int, h2);
                }

            // P -> per-wave LDS row q=l31: pairs (2a,2a+1) are k-contiguous runs of 4
#pragma unroll
            for (int kb = 0; kb < 2; ++kb)
#pragma unroll
                for (int a = 0; a < 4; ++a) {
                    uint2v v2;
                    v2[0] = pk[kb * 8 + 2 * a];
                    v2[1] = pk[kb * 8 + 2 * a + 1];
                    *(uint2v*)&Pl[w][l31][kb * 32 + 4 * h + 8 * a] = v2;
                }

            // PV: 4 k-chunks of 16; A-frag = contiguous 8 f16 from Pl (same
            // assumed k-map as V's B-frag => layout-guess-invariant)
#pragma unroll
            for (int m = 0; m < 4; ++m) {
                union { unsigned int u[4]; half8 h8; } pau;
                *(uint2v*)&pau.u[0] = *(const uint2v*)&Pl[w][l31][m * 16 + 8 * h];
                *(uint2v*)&pau.u[2] = *(const uint2v*)&Pl[w][l31][m * 16 + 8 * h + 4];
                const half8 pa = pau.h8;
                __builtin_amdgcn_s_setprio(1);
#pragma unroll
                for (int d = 0; d < 2; ++d) {
                    const int row = d * 32 + l31;
                    const half8 bv = *(const half8*)&Vl[tix][row * 64
                                       + (((2 * m + h) ^ swz8(row)) * 8)];
                    o[d] = __builtin_amdgcn_mfma_f32_32x32x16_f16(pa, bv, o[d], 0, 0, 0);
                }
                __builtin_amdgcn_s_setprio(0);
            }
        }

        asm volatile("s_waitcnt vmcnt(0)" ::: "memory");
        __syncthreads();
    }

    // partials: O as packed f16 pairs (identity layout), (m,l) f32 per q
    const size_t job = (size_t)b * 36 + i;
#pragma unroll
    for (int d = 0; d < 2; ++d)
#pragma unroll
        for (int rp = 0; rp < 8; ++rp) {
            auto h2 = __builtin_amdgcn_cvt_pkrtz(o[d][2 * rp], o[d][2 * rp + 1]);
            partO[(((job * 4 + w) * 2 + d) * 8 + rp) * 64 + lane]
                = __builtin_bit_cast(unsigned int, h2);
        }
    if (lane < 32) {
        partML[(job * 4 + w) * 64 + 2 * l31 + 0] = m2;
        partML[(job * 4 + w) * 64 + 2 * l31 + 1] = lsum;
    }
}

// ---------------------------------------------------------------------------
// combine: grid (8,16) x 256. Wave w <-> part wave w (identity layout).
// ---------------------------------------------------------------------------
__global__ __launch_bounds__(256) void attn_comb_kernel(
    const unsigned int* __restrict__ partO, const float* __restrict__ partML,
    float* __restrict__ out)
{
    __shared__ float mlds[4][64];

    const int tid = threadIdx.x, lane = tid & 63, w = tid >> 6;
    const int l31 = lane & 31, h = lane >> 5;
    const int qi = blockIdx.x, b = blockIdx.y;
    const int nch = qi + 1;
    const int starts[8] = {0, 1, 3, 6, 10, 15, 21, 28};
    const int st = starts[qi];

    float M[16];
#pragma unroll
    for (int r = 0; r < 16; ++r) M[r] = -1e30f;
    for (int c = 0; c < nch; ++c) {
        const size_t job = (size_t)b * 36 + st + c;
        mlds[w][lane] = partML[(job * 4 + w) * 64 + lane];
        asm volatile("s_waitcnt lgkmcnt(0)" ::: "memory");
        __builtin_amdgcn_sched_barrier(0);
#pragma unroll
        for (int r = 0; r < 16; ++r) {
            const int q = (r & 3) + 8 * (r >> 2) + 4 * h;
            M[r] = fmaxf(M[r], mlds[w][2 * q]);
        }
    }

    float L[16];
    float acc[2][16];
#pragma unroll
    for (int r = 0; r < 16; ++r) L[r] = 0.f;
#pragma unroll
    for (int d = 0; d < 2; ++d)
#pragma unroll
        for (int r = 0; r < 16; ++r) acc[d][r] = 0.f;

    for (int c = 0; c < nch; ++c) {
        const size_t job = (size_t)b * 36 + st + c;
        mlds[w][lane] = partML[(job * 4 + w) * 64 + lane];
        asm volatile("s_waitcnt lgkmcnt(0)" ::: "memory");
        __builtin_amdgcn_sched_barrier(0);
        float sc[16];
#pragma unroll
        for (int r = 0; r < 16; ++r) {
            const int q = (r & 3) + 8 * (r >> 2) + 4 * h;
            sc[r] = exp2f(mlds[w][2 * q] - M[r]);
            L[r] += mlds[w][2 * q + 1] * sc[r];
        }
#pragma unroll
        for (int d = 0; d < 2; ++d)
#pragma unroll
            for (int rp = 0; rp < 8; ++rp) {
                union { unsigned int u; _Float16 hh[2]; } cv;
                cv.u = partO[(((job * 4 + w) * 2 + d) * 8 + rp) * 64 + lane];
                acc[d][2 * rp]     += (float)cv.hh[0] * sc[2 * rp];
                acc[d][2 * rp + 1] += (float)cv.hh[1] * sc[2 * rp + 1];
            }
    }

#pragma unroll
    for (int d = 0; d < 2; ++d)
#pragma unroll
        for (int r = 0; r < 16; ++r) {
            const int q = qi * 128 + w * 32 + (r & 3) + 8 * (r >> 2) + 4 * h;
            out[((size_t)(b * NT + q)) * NH + d * 32 + l31] = acc[d][r] / L[r];
        }
}

extern "C" void kernel_launch(void* const* d_in, const int* in_sizes, int n_in,
                              void* d_out, int out_size, void* d_ws, size_t ws_size,
                              hipStream_t stream) {
    const float* x  = (const float*)d_in[0];
    const float* Wk = (const float*)d_in[1];
    const float* Wq = (const float*)d_in[2];
    const float* Wv = (const float*)d_in[3];

    _Float16* Qb = (_Float16*)d_ws;                        // 2 MB
    _Float16* Kb = Qb + (size_t)NB * NT * NH;              // 2 MB
    _Float16* Vt = Kb + (size_t)NB * NT * NH;              // 2 MB (transposed V)
    _Float16* Wt = Vt + (size_t)NB * NT * NH;              // 288 KB
    unsigned int* partO = (unsigned int*)((char*)d_ws + (size_t)16 * 1024 * 1024); // 9.4 MB
    float*        partML = (float*)((char*)d_ws + (size_t)32 * 1024 * 1024);       // 590 KB

    wtrans_kernel<<<dim3(48, 3), dim3(256), 0, stream>>>(Wq, Wk, Wv, Wt);
    proj_kernel<<<dim3(512), dim3(256), 0, stream>>>(x, Wt, Qb, Kb, Vt);
    attn_part_kernel<<<dim3(36, 16), dim3(256), 0, stream>>>(Qb, Kb, Vt, partO, partML);
    attn_comb_kernel<<<dim3(8, 16), dim3(256), 0, stream>>>(partO, partML, (float*)d_out);
}